// Round 1
// baseline (418.258 us; speedup 1.0000x reference)
//
#include <hip/hip_runtime.h>
#include <hip/hip_bf16.h>

// Problem constants
constexpr int kB   = 2;
constexpr int kS   = 2048;
constexpr int kD   = 1024;
constexpr int kH   = 16;
constexpr int kDh  = 64;
constexpr int kBS  = kB * kS;          // 4096 rows
constexpr float kScale = 0.125f;       // 1/sqrt(64)

typedef __attribute__((ext_vector_type(8))) short short8;   // 8 bf16 = 4 VGPRs
typedef __attribute__((ext_vector_type(4))) float floatx4;  // MFMA acc

__device__ inline unsigned short f2b(float f) {
    __hip_bfloat16 h = __float2bfloat16(f);
    return *reinterpret_cast<unsigned short*>(&h);
}

__device__ inline floatx4 mfma16(short8 a, short8 b, floatx4 c) {
    return __builtin_amdgcn_mfma_f32_16x16x32_bf16(a, b, c, 0, 0, 0);
}

// ---------------------------------------------------------------------------
// K0: fp32 -> bf16 conversion of x (4M elems) and the 4 weights (4 x 1M elems)
// ---------------------------------------------------------------------------
__global__ void convert_kernel(const float* __restrict__ x,
                               const float* __restrict__ wq, const float* __restrict__ wk,
                               const float* __restrict__ wv, const float* __restrict__ wo,
                               unsigned short* __restrict__ xb, unsigned short* __restrict__ wb) {
    int gid = blockIdx.x * blockDim.x + threadIdx.x;   // 2,097,152 threads
    long i4 = (long)gid * 4;
    const float* src;
    unsigned short* dst;
    long off;
    if (i4 < (long)kBS * kD) {          // x segment: 4,194,304 elems
        src = x; dst = xb; off = i4;
    } else {
        long w = i4 - (long)kBS * kD;   // weight segment: 4 x 1,048,576
        int sel = (int)(w >> 20);
        off = w & 1048575;
        src = (sel == 0) ? wq : (sel == 1) ? wk : (sel == 2) ? wv : wo;
        dst = wb + (long)sel * 1048576;
    }
    float4 v = *(const float4*)(src + off);
    ushort4 o;
    o.x = f2b(v.x); o.y = f2b(v.y); o.z = f2b(v.z); o.w = f2b(v.w);
    *(ushort4*)(dst + off) = o;
}

// ---------------------------------------------------------------------------
// K1: NT GEMM  C[M,N] = A[M,K] @ B[N,K]^T   (bf16 in, fp32 accum)
// MODE 0: write bf16 C (z selects weight & output slab, for Q/K/V)
// MODE 1: write fp32 C + residual (for out-projection)
// 128x128 tile, BK=32, 4 waves each doing 64x64 via 4x4 MFMA 16x16x32 tiles.
// LDS leading dim padded 32->40 shorts to break the 8-way frag-read conflict.
// ---------------------------------------------------------------------------
template <int MODE>
__launch_bounds__(256, 2)
__global__ void gemm_nt(const unsigned short* __restrict__ A,
                        const unsigned short* __restrict__ Bw,
                        void* __restrict__ Cout,
                        const float* __restrict__ resid,
                        int M, int N, int K) {
    constexpr int BM = 128, BN = 128, BK = 32;
    constexpr int LDA = 40;  // padded LDS stride (shorts)
    __shared__ __align__(16) unsigned short As[BM * LDA];
    __shared__ __align__(16) unsigned short Bs[BN * LDA];

    const int z  = blockIdx.z;
    const unsigned short* Bp = Bw + (size_t)z * N * K;
    const int m0 = blockIdx.y * BM, n0 = blockIdx.x * BN;
    const int tid  = threadIdx.x;
    const int lane = tid & 63, w = tid >> 6;
    const int wm = w >> 1, wn = w & 1;
    const int quad = lane >> 4, l16 = lane & 15;

    floatx4 acc[4][4] = {};

    // staging: thread t loads 16 contiguous bf16 of one row for A and B
    const int lrow = tid >> 1, lcol = (tid & 1) * 16;
    const uint4* Ag = (const uint4*)(A  + (size_t)(m0 + lrow) * K + lcol);
    const uint4* Bg = (const uint4*)(Bp + (size_t)(n0 + lrow) * K + lcol);
    uint4* Asd = (uint4*)(As + lrow * LDA + lcol);
    uint4* Bsd = (uint4*)(Bs + lrow * LDA + lcol);

    for (int k0 = 0; k0 < K; k0 += BK) {
        uint4 a0 = Ag[k0 / 8], a1 = Ag[k0 / 8 + 1];
        uint4 b0 = Bg[k0 / 8], b1 = Bg[k0 / 8 + 1];
        __syncthreads();                  // previous iteration's reads done
        Asd[0] = a0; Asd[1] = a1;
        Bsd[0] = b0; Bsd[1] = b1;
        __syncthreads();

        short8 af[4], bf[4];
#pragma unroll
        for (int i = 0; i < 4; i++)
            af[i] = *(const short8*)(As + (wm * 64 + i * 16 + l16) * LDA + quad * 8);
#pragma unroll
        for (int j = 0; j < 4; j++)
            bf[j] = *(const short8*)(Bs + (wn * 64 + j * 16 + l16) * LDA + quad * 8);
#pragma unroll
        for (int i = 0; i < 4; i++)
#pragma unroll
            for (int j = 0; j < 4; j++)
                acc[i][j] = mfma16(af[i], bf[j], acc[i][j]);
    }

    // epilogue: D[row = quad*4 + r][col = l16] per 16x16 tile
#pragma unroll
    for (int i = 0; i < 4; i++)
#pragma unroll
        for (int j = 0; j < 4; j++) {
            const int row = m0 + wm * 64 + i * 16 + quad * 4;
            const int col = n0 + wn * 64 + j * 16 + l16;
#pragma unroll
            for (int r = 0; r < 4; r++) {
                float v = acc[i][j][r];
                if (MODE == 0) {
                    ((unsigned short*)Cout)[(size_t)z * M * N + (size_t)(row + r) * N + col] = f2b(v);
                } else {
                    size_t idx = (size_t)(row + r) * N + col;
                    ((float*)Cout)[idx] = v + resid[idx];
                }
            }
        }
}

// ---------------------------------------------------------------------------
// K2: column-softmax stats. For each (b,h,key): m_k = max_q s, invl = 1/sum_q exp(s-m)
// Each wave owns 16 keys (B-frag held in regs), loops all 2048 q in 16-row tiles.
// D[q=quad*4+r][key=l16]; online (m,l) per lane, butterfly-combine quads at end.
// ---------------------------------------------------------------------------
__launch_bounds__(256, 2)
__global__ void stats_kernel(const unsigned short* __restrict__ Qb,
                             const unsigned short* __restrict__ Kb,
                             float* __restrict__ mbuf, float* __restrict__ invl) {
    const int bh = blockIdx.y;
    const int b = bh >> 4, h = bh & 15;
    const int tid = threadIdx.x, lane = tid & 63, w = tid >> 6;
    const int quad = lane >> 4, l16 = lane & 15;
    const int key = blockIdx.x * 64 + w * 16 + l16;

    const unsigned short* Krow = Kb + (size_t)(b * kS + key) * kD + h * kDh;
    short8 bk0 = *(const short8*)(Krow + quad * 8);
    short8 bk1 = *(const short8*)(Krow + 32 + quad * 8);

    const unsigned short* Qbase = Qb + (size_t)(b * kS) * kD + h * kDh;
    float m = -INFINITY, l = 0.f;
    for (int q0 = 0; q0 < kS; q0 += 16) {
        const unsigned short* Qrow = Qbase + (size_t)(q0 + l16) * kD;
        short8 a0 = *(const short8*)(Qrow + quad * 8);
        short8 a1 = *(const short8*)(Qrow + 32 + quad * 8);
        floatx4 sc = {0.f, 0.f, 0.f, 0.f};
        sc = mfma16(a0, bk0, sc);
        sc = mfma16(a1, bk1, sc);
        float v0 = sc[0] * kScale, v1 = sc[1] * kScale, v2 = sc[2] * kScale, v3 = sc[3] * kScale;
        float tm = fmaxf(fmaxf(v0, v1), fmaxf(v2, v3));
        float nm = fmaxf(m, tm);
        l = l * __expf(m - nm) + __expf(v0 - nm) + __expf(v1 - nm) + __expf(v2 - nm) + __expf(v3 - nm);
        m = nm;
    }
    // combine the 4 lanes (quads) sharing each key column
#pragma unroll
    for (int off = 16; off <= 32; off <<= 1) {
        float om = __shfl_xor(m, off, 64);
        float ol = __shfl_xor(l, off, 64);
        float nm = fmaxf(m, om);
        l = l * __expf(m - nm) + ol * __expf(om - nm);
        m = nm;
    }
    if (quad == 0) {
        mbuf[(size_t)bh * kS + key] = m;
        invl[(size_t)bh * kS + key] = 1.0f / l;
    }
}

// ---------------------------------------------------------------------------
// K3: ctx[b,q,h*64+d] = sum_k exp(s[q,k]-m_k)*invl_k * V[b,k,h*64+d]
// Wave owns 16 q rows (Q frags in regs). Loop k in 32-tiles:
//   S via MFMA -> P = exp(s*scale - m)*invl -> LDS (C-layout -> A-layout) ->
//   PV MFMA vs LDS-transposed V tile. Output bf16 for the out-proj GEMM.
// ---------------------------------------------------------------------------
__launch_bounds__(256, 2)
__global__ void ctx_kernel(const unsigned short* __restrict__ Qb,
                           const unsigned short* __restrict__ Kb,
                           const unsigned short* __restrict__ Vb,
                           const float* __restrict__ mbuf, const float* __restrict__ invl,
                           unsigned short* __restrict__ Ctx) {
    constexpr int LDV = 40;  // padded stride
    __shared__ __align__(16) unsigned short VT[64 * LDV];      // V^T tile [d][k]
    __shared__ __align__(16) unsigned short Pt[4][16 * LDV];   // per-wave P tile [q][k]

    const int bh = blockIdx.y;
    const int b = bh >> 4, h = bh & 15;
    const int tid = threadIdx.x, lane = tid & 63, w = tid >> 6;
    const int quad = lane >> 4, l16 = lane & 15;
    const int qbase = blockIdx.x * 64 + w * 16;

    const unsigned short* Qrow = Qb + (size_t)(b * kS + qbase + l16) * kD + h * kDh;
    short8 aq0 = *(const short8*)(Qrow + quad * 8);
    short8 aq1 = *(const short8*)(Qrow + 32 + quad * 8);

    floatx4 acc[4] = {};

    const int vkey = tid >> 3;        // 0..31
    const int vd   = (tid & 7) * 8;   // 0..56
    const unsigned short* Kbase = Kb + (size_t)(b * kS) * kD + h * kDh;
    const unsigned short* Vbase = Vb + (size_t)(b * kS) * kD + h * kDh;
    const float* mrow = mbuf + (size_t)bh * kS;
    const float* irow = invl + (size_t)bh * kS;

    for (int k0 = 0; k0 < kS; k0 += 32) {
        // stage V^T tile: thread loads 8 contiguous bf16 of one V row
        uint4 vv = *(const uint4*)(Vbase + (size_t)(k0 + vkey) * kD + vd);
        unsigned short vs[8];
        *(uint4*)vs = vv;

        // K fragments for the two 16-key column tiles
        short8 bk[2][2];
#pragma unroll
        for (int c = 0; c < 2; c++) {
            const unsigned short* Krow = Kbase + (size_t)(k0 + c * 16 + l16) * kD;
            bk[c][0] = *(const short8*)(Krow + quad * 8);
            bk[c][1] = *(const short8*)(Krow + 32 + quad * 8);
        }

        __syncthreads();   // previous iteration's LDS reads complete
#pragma unroll
        for (int ii = 0; ii < 8; ii++)
            VT[(vd + ii) * LDV + vkey] = vs[ii];

        // S tiles + softmax transform + write P in [q][k] layout
#pragma unroll
        for (int c = 0; c < 2; c++) {
            floatx4 sc = {0.f, 0.f, 0.f, 0.f};
            sc = mfma16(aq0, bk[c][0], sc);
            sc = mfma16(aq1, bk[c][1], sc);
            const int key = k0 + c * 16 + l16;
            const float mv = mrow[key];
            const float iv = irow[key];
#pragma unroll
            for (int r = 0; r < 4; r++) {
                float p = __expf(sc[r] * kScale - mv) * iv;
                Pt[w][(quad * 4 + r) * LDV + c * 16 + l16] = f2b(p);
            }
        }
        __syncthreads();   // VT + P visible

        // PV: A-frag = P[q=l16][kk=quad*8+j], B-frag = V[kk][d] from VT
        short8 ap = *(const short8*)(&Pt[w][l16 * LDV + quad * 8]);
#pragma unroll
        for (int t = 0; t < 4; t++) {
            short8 bv = *(const short8*)(VT + (t * 16 + l16) * LDV + quad * 8);
            acc[t] = mfma16(ap, bv, acc[t]);
        }
    }

#pragma unroll
    for (int t = 0; t < 4; t++)
#pragma unroll
        for (int r = 0; r < 4; r++) {
            Ctx[(size_t)(b * kS + qbase + quad * 4 + r) * kD + h * kDh + t * 16 + l16] =
                f2b(acc[t][r]);
        }
}

// ---------------------------------------------------------------------------
// K4: row LayerNorm: out = (R - mu) * rsqrt(var + eps) * gamma + beta
// One block per row (1024 floats), 256 threads x float4.
// ---------------------------------------------------------------------------
__global__ void ln_kernel(const float* __restrict__ R, const float* __restrict__ gamma,
                          const float* __restrict__ beta, float* __restrict__ out) {
    const int row = blockIdx.x;
    const int tid = threadIdx.x;
    const float4 v = ((const float4*)(R + (size_t)row * kD))[tid];
    float s  = v.x + v.y + v.z + v.w;
    float ss = v.x * v.x + v.y * v.y + v.z * v.z + v.w * v.w;
#pragma unroll
    for (int off = 32; off > 0; off >>= 1) {
        s  += __shfl_down(s, off, 64);
        ss += __shfl_down(ss, off, 64);
    }
    __shared__ float ws_s[4], ws_ss[4];
    __shared__ float mu_sh, inv_sh;
    const int lane = tid & 63, w = tid >> 6;
    if (lane == 0) { ws_s[w] = s; ws_ss[w] = ss; }
    __syncthreads();
    if (tid == 0) {
        float S1 = ws_s[0] + ws_s[1] + ws_s[2] + ws_s[3];
        float S2 = ws_ss[0] + ws_ss[1] + ws_ss[2] + ws_ss[3];
        float mu = S1 * (1.0f / kD);
        float var = S2 * (1.0f / kD) - mu * mu;
        mu_sh = mu;
        inv_sh = rsqrtf(var + 1e-5f);
    }
    __syncthreads();
    const float mu = mu_sh, inv = inv_sh;
    const float4 g  = ((const float4*)gamma)[tid];
    const float4 bb = ((const float4*)beta)[tid];
    float4 o;
    o.x = (v.x - mu) * inv * g.x + bb.x;
    o.y = (v.y - mu) * inv * g.y + bb.y;
    o.z = (v.z - mu) * inv * g.z + bb.z;
    o.w = (v.w - mu) * inv * g.w + bb.w;
    ((float4*)(out + (size_t)row * kD))[tid] = o;
}

// ---------------------------------------------------------------------------
// Workspace layout (needs ~64.5 MB):
//   [0,   8MB)  Xb   bf16 [4096,1024]
//   [8,  16MB)  Wb   bf16 wq|wk|wv|wo, 1M elems each
//   [16, 40MB)  QKV  bf16 Q|K|V, 4M elems each
//   [40, 48MB)  Ctx  bf16 [4096,1024]
//   [48, 64MB)  R    fp32 [4096,1024]  (out-proj + residual)
//   [64MB, +256KB) mbuf fp32 [32,2048]
//   [.., +256KB)   invl fp32 [32,2048]
// ---------------------------------------------------------------------------
extern "C" void kernel_launch(void* const* d_in, const int* in_sizes, int n_in,
                              void* d_out, int out_size, void* d_ws, size_t ws_size,
                              hipStream_t stream) {
    const float* x     = (const float*)d_in[0];
    const float* wq    = (const float*)d_in[1];
    const float* wk    = (const float*)d_in[2];
    const float* wv    = (const float*)d_in[3];
    const float* wo    = (const float*)d_in[4];
    const float* gamma = (const float*)d_in[5];
    const float* beta  = (const float*)d_in[6];
    float* out = (float*)d_out;

    char* ws = (char*)d_ws;
    unsigned short* Xb  = (unsigned short*)(ws);
    unsigned short* Wb  = (unsigned short*)(ws + (8u  << 20));
    unsigned short* QKV = (unsigned short*)(ws + (16u << 20));
    unsigned short* Qb  = QKV;
    unsigned short* Kb  = QKV + (size_t)kBS * kD;
    unsigned short* Vb  = QKV + (size_t)2 * kBS * kD;
    unsigned short* Ctx = (unsigned short*)(ws + (40u << 20));
    float* R    = (float*)(ws + (48u << 20));
    float* mbuf = (float*)(ws + (64u << 20));
    float* invl = (float*)(ws + (64u << 20) + 262144);

    // K0: fp32 -> bf16 (x + 4 weights), exact grid
    convert_kernel<<<8192, 256, 0, stream>>>(x, wq, wk, wv, wo, Xb, Wb);

    // K1: Q,K,V projections in one launch (z = 0,1,2)
    gemm_nt<0><<<dim3(kD / 128, kBS / 128, 3), 256, 0, stream>>>(
        Xb, Wb, QKV, nullptr, kBS, kD, kD);

    // K2: per-key softmax stats
    stats_kernel<<<dim3(kS / 64, kB * kH), 256, 0, stream>>>(Qb, Kb, mbuf, invl);

    // K3: attention context
    ctx_kernel<<<dim3(kS / 64, kB * kH), 256, 0, stream>>>(Qb, Kb, Vb, mbuf, invl, Ctx);

    // K4: out-projection + residual (fp32 out)
    gemm_nt<1><<<dim3(kD / 128, kBS / 128, 1), 256, 0, stream>>>(
        Ctx, Wb + (size_t)3 * kD * kD, R, x, kBS, kD, kD);

    // K5: LayerNorm
    ln_kernel<<<kBS, 256, 0, stream>>>(R, gamma, beta, out);
}

// Round 2
// 400.156 us; speedup vs baseline: 1.0452x; 1.0452x over previous
//
#include <hip/hip_runtime.h>
#include <hip/hip_bf16.h>

// Problem constants
constexpr int kB   = 2;
constexpr int kS   = 2048;
constexpr int kD   = 1024;
constexpr int kH   = 16;
constexpr int kDh  = 64;
constexpr int kBS  = kB * kS;          // 4096 rows

typedef __attribute__((ext_vector_type(8))) short short8;   // 8 bf16 = 4 VGPRs
typedef __attribute__((ext_vector_type(4))) float floatx4;  // MFMA acc

__device__ inline unsigned short f2b(float f) {
    __hip_bfloat16 h = __float2bfloat16(f);
    return *reinterpret_cast<unsigned short*>(&h);
}

__device__ inline floatx4 mfma16(short8 a, short8 b, floatx4 c) {
    return __builtin_amdgcn_mfma_f32_16x16x32_bf16(a, b, c, 0, 0, 0);
}

// ---------------------------------------------------------------------------
// K0: fp32 -> bf16 conversion of x (4M elems) and the 4 weights (4 x 1M elems)
// ---------------------------------------------------------------------------
__global__ void convert_kernel(const float* __restrict__ x,
                               const float* __restrict__ wq, const float* __restrict__ wk,
                               const float* __restrict__ wv, const float* __restrict__ wo,
                               unsigned short* __restrict__ xb, unsigned short* __restrict__ wb) {
    int gid = blockIdx.x * blockDim.x + threadIdx.x;
    long i4 = (long)gid * 4;
    const float* src;
    unsigned short* dst;
    long off;
    if (i4 < (long)kBS * kD) {
        src = x; dst = xb; off = i4;
    } else {
        long w = i4 - (long)kBS * kD;
        int sel = (int)(w >> 20);
        off = w & 1048575;
        src = (sel == 0) ? wq : (sel == 1) ? wk : (sel == 2) ? wv : wo;
        dst = wb + (long)sel * 1048576;
    }
    float4 v = *(const float4*)(src + off);
    ushort4 o;
    o.x = f2b(v.x); o.y = f2b(v.y); o.z = f2b(v.z); o.w = f2b(v.w);
    *(ushort4*)(dst + off) = o;
}

// ---------------------------------------------------------------------------
// K1: NT GEMM  C[M,N] = A[M,K] @ B[N,K]^T   (bf16 in, fp32 accum)
// MODE 0: write bf16 C; z==0 (Q) additionally scaled by 1/sqrt(Dh)=0.125
// MODE 1: write fp32 C + residual (out-projection)
// ---------------------------------------------------------------------------
template <int MODE>
__launch_bounds__(256, 2)
__global__ void gemm_nt(const unsigned short* __restrict__ A,
                        const unsigned short* __restrict__ Bw,
                        void* __restrict__ Cout,
                        const float* __restrict__ resid,
                        int M, int N, int K) {
    constexpr int BM = 128, BN = 128, BK = 32;
    constexpr int LDA = 40;  // padded LDS stride (shorts)
    __shared__ __align__(16) unsigned short As[BM * LDA];
    __shared__ __align__(16) unsigned short Bs[BN * LDA];

    const int z  = blockIdx.z;
    const unsigned short* Bp = Bw + (size_t)z * N * K;
    const int m0 = blockIdx.y * BM, n0 = blockIdx.x * BN;
    const int tid  = threadIdx.x;
    const int lane = tid & 63, w = tid >> 6;
    const int wm = w >> 1, wn = w & 1;
    const int quad = lane >> 4, l16 = lane & 15;

    floatx4 acc[4][4] = {};

    const int lrow = tid >> 1, lcol = (tid & 1) * 16;
    const uint4* Ag = (const uint4*)(A  + (size_t)(m0 + lrow) * K + lcol);
    const uint4* Bg = (const uint4*)(Bp + (size_t)(n0 + lrow) * K + lcol);
    uint4* Asd = (uint4*)(As + lrow * LDA + lcol);
    uint4* Bsd = (uint4*)(Bs + lrow * LDA + lcol);

    for (int k0 = 0; k0 < K; k0 += BK) {
        uint4 a0 = Ag[k0 / 8], a1 = Ag[k0 / 8 + 1];
        uint4 b0 = Bg[k0 / 8], b1 = Bg[k0 / 8 + 1];
        __syncthreads();
        Asd[0] = a0; Asd[1] = a1;
        Bsd[0] = b0; Bsd[1] = b1;
        __syncthreads();

        short8 af[4], bf[4];
#pragma unroll
        for (int i = 0; i < 4; i++)
            af[i] = *(const short8*)(As + (wm * 64 + i * 16 + l16) * LDA + quad * 8);
#pragma unroll
        for (int j = 0; j < 4; j++)
            bf[j] = *(const short8*)(Bs + (wn * 64 + j * 16 + l16) * LDA + quad * 8);
#pragma unroll
        for (int i = 0; i < 4; i++)
#pragma unroll
            for (int j = 0; j < 4; j++)
                acc[i][j] = mfma16(af[i], bf[j], acc[i][j]);
    }

#pragma unroll
    for (int i = 0; i < 4; i++)
#pragma unroll
        for (int j = 0; j < 4; j++) {
            const int row = m0 + wm * 64 + i * 16 + quad * 4;
            const int col = n0 + wn * 64 + j * 16 + l16;
#pragma unroll
            for (int r = 0; r < 4; r++) {
                float v = acc[i][j][r];
                if (MODE == 0) {
                    if (z == 0) v *= 0.125f;   // fold attention scale into Q
                    ((unsigned short*)Cout)[(size_t)z * M * N + (size_t)(row + r) * N + col] = f2b(v);
                } else {
                    size_t idx = (size_t)(row + r) * N + col;
                    ((float*)Cout)[idx] = v + resid[idx];
                }
            }
        }
}

// ---------------------------------------------------------------------------
// K2: column-softmax denominators. invl[bh,k] = 1 / sum_q exp(s[q,k]).
// No max subtraction: |s| <~ 20, exp range fp32-safe.
// Wave owns 16 keys (B-frag in regs), loops all 2048 q. Barrier-free.
// ---------------------------------------------------------------------------
__launch_bounds__(256, 4)
__global__ void stats_kernel(const unsigned short* __restrict__ Qb,
                             const unsigned short* __restrict__ Kb,
                             float* __restrict__ invl) {
    const int bh = blockIdx.y;
    const int b = bh >> 4, h = bh & 15;
    const int tid = threadIdx.x, lane = tid & 63, w = tid >> 6;
    const int quad = lane >> 4, l16 = lane & 15;
    const int key = blockIdx.x * 64 + w * 16 + l16;

    const unsigned short* Krow = Kb + (size_t)(b * kS + key) * kD + h * kDh;
    short8 bk0 = *(const short8*)(Krow + quad * 8);
    short8 bk1 = *(const short8*)(Krow + 32 + quad * 8);

    const unsigned short* Qbase = Qb + (size_t)(b * kS) * kD + h * kDh;
    float l = 0.f;
    for (int q0 = 0; q0 < kS; q0 += 16) {
        const unsigned short* Qrow = Qbase + (size_t)(q0 + l16) * kD;
        short8 a0 = *(const short8*)(Qrow + quad * 8);
        short8 a1 = *(const short8*)(Qrow + 32 + quad * 8);
        floatx4 sc = {0.f, 0.f, 0.f, 0.f};
        sc = mfma16(a0, bk0, sc);
        sc = mfma16(a1, bk1, sc);
        l += __expf(sc[0]) + __expf(sc[1]) + __expf(sc[2]) + __expf(sc[3]);
    }
    // sum the 4 quads sharing each key column
    l += __shfl_xor(l, 16, 64);
    l += __shfl_xor(l, 32, 64);
    if (quad == 0) invl[(size_t)bh * kS + key] = 1.0f / l;
}

// ---------------------------------------------------------------------------
// K2b: VT[bh][d][k] = V[b][k][h*64+d] * invl[bh][k]   (pre-scaled V^T)
// 64k x 64d tile per block via LDS (stride 65: all accesses <=2-way).
// ---------------------------------------------------------------------------
__global__ void vt_kernel(const unsigned short* __restrict__ Vb,
                          const float* __restrict__ invl,
                          unsigned short* __restrict__ VT) {
    __shared__ unsigned short tile[64 * 65];
    const int bh = blockIdx.y, b = bh >> 4, h = bh & 15;
    const int k0 = blockIdx.x * 64;
    const int tid = threadIdx.x;
    const int kr = tid >> 2, dc = (tid & 3) * 16;

    const float iv = invl[(size_t)bh * kS + k0 + kr];
    const unsigned short* src = Vb + (size_t)(b * kS + k0 + kr) * kD + h * kDh + dc;
    uint4 v0 = *(const uint4*)(src);
    uint4 v1 = *(const uint4*)(src + 8);
    unsigned short vs[16];
    *(uint4*)(vs) = v0; *(uint4*)(vs + 8) = v1;
#pragma unroll
    for (int i = 0; i < 16; i++) {
        __hip_bfloat16 hv = *reinterpret_cast<__hip_bfloat16*>(&vs[i]);
        tile[kr * 65 + dc + i] = f2b(__bfloat162float(hv) * iv);
    }
    __syncthreads();
    const int d = tid >> 2, kc = (tid & 3) * 16;
    unsigned short os[16];
#pragma unroll
    for (int j = 0; j < 16; j++) os[j] = tile[(kc + j) * 65 + d];
    unsigned short* dst = VT + (size_t)bh * kDh * kS + (size_t)d * kS + k0 + kc;
    *(uint4*)(dst)     = *(uint4*)(os);
    *(uint4*)(dst + 8) = *(uint4*)(os + 8);
}

// ---------------------------------------------------------------------------
// K3: ctx = exp(S) @ VT^T, barrier-free.
// Block = 4 waves; wave owns 32 q x 64 d for one bh. K-loop chunk = 64 keys:
//   16 S-MFMAs -> exp -> P to own LDS region ([q][k] layout, stride 72 +
//   XOR-16 swizzle: writes hit all 32 banks exactly 2-way) -> 16 PV-MFMAs
//   with B-frags straight from global VT (L1-shared across waves).
// ---------------------------------------------------------------------------
__launch_bounds__(256, 2)
__global__ void ctx_kernel(const unsigned short* __restrict__ Qb,
                           const unsigned short* __restrict__ Kb,
                           const unsigned short* __restrict__ VT,
                           unsigned short* __restrict__ Ctx) {
    constexpr int LDP = 72;
    __shared__ __align__(16) unsigned short Pt[4][32 * LDP];

    const int bh = blockIdx.y;
    const int b = bh >> 4, h = bh & 15;
    const int tid = threadIdx.x, lane = tid & 63, w = tid >> 6;
    const int quad = lane >> 4, l16 = lane & 15;
    const int qbase = blockIdx.x * 128 + w * 32;

    short8 aq[2][2];
#pragma unroll
    for (int s = 0; s < 2; s++) {
        const unsigned short* Qrow = Qb + (size_t)(b * kS + qbase + s * 16 + l16) * kD + h * kDh;
        aq[s][0] = *(const short8*)(Qrow + quad * 8);
        aq[s][1] = *(const short8*)(Qrow + 32 + quad * 8);
    }
    floatx4 acc[2][4] = {};

    const unsigned short* Kbase = Kb + (size_t)(b * kS) * kD + h * kDh;
    const unsigned short* VTb   = VT + (size_t)bh * kDh * kS;
    unsigned short* P = Pt[w];
    const int sw_w = quad * 16;          // write swizzle: ((row>>2)&3)*16, row=s*16+quad*4+r
    const int sw_r = (l16 >> 2) * 16;    // read  swizzle: ((row>>2)&3)*16, row=s*16+l16

    for (int k0 = 0; k0 < kS; k0 += 64) {
        short8 bk[4][2];
#pragma unroll
        for (int c = 0; c < 4; c++) {
            const unsigned short* Krow = Kbase + (size_t)(k0 + c * 16 + l16) * kD;
            bk[c][0] = *(const short8*)(Krow + quad * 8);
            bk[c][1] = *(const short8*)(Krow + 32 + quad * 8);
        }
        // S tiles -> exp -> P (own region, no barrier)
#pragma unroll
        for (int s = 0; s < 2; s++)
#pragma unroll
            for (int c = 0; c < 4; c++) {
                floatx4 sc = {0.f, 0.f, 0.f, 0.f};
                sc = mfma16(aq[s][0], bk[c][0], sc);
                sc = mfma16(aq[s][1], bk[c][1], sc);
#pragma unroll
                for (int r = 0; r < 4; r++) {
                    const int row = s * 16 + quad * 4 + r;
                    const int col = (c * 16 + l16) ^ sw_w;
                    P[row * LDP + col] = f2b(__expf(sc[r]));
                }
            }
        // PV: A-frags from own P region, B-frags from global VT
#pragma unroll
        for (int s = 0; s < 2; s++) {
            short8 ap[2];
#pragma unroll
            for (int h2 = 0; h2 < 2; h2++) {
                const int col = (h2 * 32 + quad * 8) ^ sw_r;
                ap[h2] = *(const short8*)(P + (s * 16 + l16) * LDP + col);
            }
#pragma unroll
            for (int t = 0; t < 4; t++) {
                const unsigned short* Vrow = VTb + (size_t)(t * 16 + l16) * kS + k0;
                acc[s][t] = mfma16(ap[0], *(const short8*)(Vrow + quad * 8), acc[s][t]);
                acc[s][t] = mfma16(ap[1], *(const short8*)(Vrow + 32 + quad * 8), acc[s][t]);
            }
        }
    }

#pragma unroll
    for (int s = 0; s < 2; s++)
#pragma unroll
        for (int t = 0; t < 4; t++)
#pragma unroll
            for (int r = 0; r < 4; r++)
                Ctx[(size_t)(b * kS + qbase + s * 16 + quad * 4 + r) * kD + h * kDh + t * 16 + l16] =
                    f2b(acc[s][t][r]);
}

// ---------------------------------------------------------------------------
// K4: row LayerNorm
// ---------------------------------------------------------------------------
__global__ void ln_kernel(const float* __restrict__ R, const float* __restrict__ gamma,
                          const float* __restrict__ beta, float* __restrict__ out) {
    const int row = blockIdx.x;
    const int tid = threadIdx.x;
    const float4 v = ((const float4*)(R + (size_t)row * kD))[tid];
    float s  = v.x + v.y + v.z + v.w;
    float ss = v.x * v.x + v.y * v.y + v.z * v.z + v.w * v.w;
#pragma unroll
    for (int off = 32; off > 0; off >>= 1) {
        s  += __shfl_down(s, off, 64);
        ss += __shfl_down(ss, off, 64);
    }
    __shared__ float ws_s[4], ws_ss[4];
    __shared__ float mu_sh, inv_sh;
    const int lane = tid & 63, w = tid >> 6;
    if (lane == 0) { ws_s[w] = s; ws_ss[w] = ss; }
    __syncthreads();
    if (tid == 0) {
        float S1 = ws_s[0] + ws_s[1] + ws_s[2] + ws_s[3];
        float S2 = ws_ss[0] + ws_ss[1] + ws_ss[2] + ws_ss[3];
        float mu = S1 * (1.0f / kD);
        float var = S2 * (1.0f / kD) - mu * mu;
        mu_sh = mu;
        inv_sh = rsqrtf(var + 1e-5f);
    }
    __syncthreads();
    const float mu = mu_sh, inv = inv_sh;
    const float4 g  = ((const float4*)gamma)[tid];
    const float4 bb = ((const float4*)beta)[tid];
    float4 o;
    o.x = (v.x - mu) * inv * g.x + bb.x;
    o.y = (v.y - mu) * inv * g.y + bb.y;
    o.z = (v.z - mu) * inv * g.z + bb.z;
    o.w = (v.w - mu) * inv * g.w + bb.w;
    ((float4*)(out + (size_t)row * kD))[tid] = o;
}

// ---------------------------------------------------------------------------
// Workspace layout (64.25 MB, same footprint as round 1):
//   [0,   8MB)  Xb   bf16 [4096,1024]
//   [8,  16MB)  Wb   bf16 wq|wk|wv|wo
//   [16, 40MB)  QKV  bf16 Q|K|V  (Q pre-scaled by 0.125)
//   [40, 48MB)  Ctx  bf16 [4096,1024]
//   [48, 64MB)  VT   bf16 [32][64][2048] (invl-scaled V^T) -- ALIASES R:
//               gemm_nt<1> writes R here strictly after ctx's last VT read.
//   [64MB, +256KB) invl fp32 [32,2048]
// ---------------------------------------------------------------------------
extern "C" void kernel_launch(void* const* d_in, const int* in_sizes, int n_in,
                              void* d_out, int out_size, void* d_ws, size_t ws_size,
                              hipStream_t stream) {
    const float* x     = (const float*)d_in[0];
    const float* wq    = (const float*)d_in[1];
    const float* wk    = (const float*)d_in[2];
    const float* wv    = (const float*)d_in[3];
    const float* wo    = (const float*)d_in[4];
    const float* gamma = (const float*)d_in[5];
    const float* beta  = (const float*)d_in[6];
    float* out = (float*)d_out;

    char* ws = (char*)d_ws;
    unsigned short* Xb  = (unsigned short*)(ws);
    unsigned short* Wb  = (unsigned short*)(ws + (8u  << 20));
    unsigned short* QKV = (unsigned short*)(ws + (16u << 20));
    unsigned short* Qb  = QKV;
    unsigned short* Kb  = QKV + (size_t)kBS * kD;
    unsigned short* Vb  = QKV + (size_t)2 * kBS * kD;
    unsigned short* Ctx = (unsigned short*)(ws + (40u << 20));
    unsigned short* VT  = (unsigned short*)(ws + (48u << 20));
    float* R            = (float*)(ws + (48u << 20));   // aliases VT (see above)
    float* invl         = (float*)(ws + (64u << 20));

    convert_kernel<<<8192, 256, 0, stream>>>(x, wq, wk, wv, wo, Xb, Wb);

    gemm_nt<0><<<dim3(kD / 128, kBS / 128, 3), 256, 0, stream>>>(
        Xb, Wb, QKV, nullptr, kBS, kD, kD);

    stats_kernel<<<dim3(kS / 64, kB * kH), 256, 0, stream>>>(Qb, Kb, invl);

    vt_kernel<<<dim3(kS / 64, kB * kH), 256, 0, stream>>>(Vb, invl, VT);

    ctx_kernel<<<dim3(kS / 128, kB * kH), 256, 0, stream>>>(Qb, Kb, VT, Ctx);

    gemm_nt<1><<<dim3(kD / 128, kBS / 128, 1), 256, 0, stream>>>(
        Ctx, Wb + (size_t)3 * kD * kD, R, x, kBS, kD, kD);

    ln_kernel<<<kBS, 256, 0, stream>>>(R, gamma, beta, out);
}